// Round 9
// baseline (322.968 us; speedup 1.0000x reference)
//
#include <hip/hip_runtime.h>
#include <math.h>

// ---------------- geometry constants ----------------
#define NXg      192
#define PLANE_SZ (NXg*NXg)            // 36864
#define PLANES   16                   // B(2) * NR(8)
#define TOTAL    (PLANES*PLANE_SZ)
#define NT       200
#define NM       32
#define CW       96                   // central window width
#define C0       48                   // central window origin
#define W96SQ    (CW*CW)
#define A0       24                   // active domain [24,168)^2 ; outside ~0 (coef 9e-14)
#define TILE     36                   // interior tile, 16 tiles/plane -> 256 blocks
#define HALO     20                   // 2 cells/step * 10 steps
#define EXPW     76                   // TILE + 2*HALO
#define LSTR     84                   // LDS row stride
#define KSTEP    10
#define NCH      20                   // 20 chunks * 10 steps = 200
#define NSB      (38*19)              // 722 sub-blocks (2 rows x 4 cols)
#define BLK      768                  // 12 waves/CU
#define LDS_FLOATS (EXPW*LSTR)        // 6384 per level
#define LDS_FORCE  86016              // dynamic LDS > 80KiB: 1 block/CU -> all 256 co-resident
#define NRING    1120                 // ring f4-groups (1444 full - 324 interior)

struct MeasIdx { int v[NM]; };
typedef float4 f4;
typedef float2 f2;

// Agent-coherent dword access WITHOUT cache maintenance (sc1 write-through /
// coherence-point reads). No buffer_wbl2 / buffer_inv (R7's poison), and no
// RMW polling (R8's poison).
__device__ __forceinline__ float ld_coh(const float* p){
    return __hip_atomic_load((const float*)p, __ATOMIC_RELAXED, __HIP_MEMORY_SCOPE_AGENT);
}
__device__ __forceinline__ void st_coh(float* p, float v){
    __hip_atomic_store(p, v, __ATOMIC_RELAXED, __HIP_MEMORY_SCOPE_AGENT);
}
__device__ __forceinline__ int ld_flag(const int* p){
    return __hip_atomic_load((const int*)p, __ATOMIC_RELAXED, __HIP_MEMORY_SCOPE_AGENT);
}

// identical arithmetic/order to the verified round-1..8 kernels
__device__ __forceinline__ f4 frow(f2 L, f4 C, f2 Q,
                                   f4 m2, f4 m1, f4 p1, f4 p2,
                                   f4 O, f4 CF, f4 RF, f4 D2)
{
    const float s = 1.0f/12.0f;
    float v0=L.x, v1=L.y, v2=C.x, v3=C.y, v4=C.z, v5=C.w, v6=Q.x, v7=Q.y;
    float lxA = (-v0 + 16.f*v1 - 30.f*v2 + 16.f*v3 - v4)*s;
    float lxB = (-v1 + 16.f*v2 - 30.f*v3 + 16.f*v4 - v5)*s;
    float lxC = (-v2 + 16.f*v3 - 30.f*v4 + 16.f*v5 - v6)*s;
    float lxD = (-v3 + 16.f*v4 - 30.f*v5 + 16.f*v6 - v7)*s;
    float lyA = (-m2.x + 16.f*m1.x - 30.f*v2 + 16.f*p1.x - p2.x)*s;
    float lyB = (-m2.y + 16.f*m1.y - 30.f*v3 + 16.f*p1.y - p2.y)*s;
    float lyC = (-m2.z + 16.f*m1.z - 30.f*v4 + 16.f*p1.z - p2.z)*s;
    float lyD = (-m2.w + 16.f*m1.w - 30.f*v5 + 16.f*p1.w - p2.w)*s;
    f4 r;
    r.x = 2.f*v2 - O.x + CF.x*(lxA+lyA) + RF.x*D2.x;
    r.y = 2.f*v3 - O.y + CF.y*(lxB+lyB) + RF.y*D2.y;
    r.z = 2.f*v4 - O.z + CF.z*(lxC+lyC) + RF.z*D2.z;
    r.w = 2.f*v5 - O.w + CF.w*(lxD+lyD) + RF.w*D2.w;
    return r;
}

__device__ __forceinline__ f4 d2c(f4 c, f4 b, f4 a){
    f4 r;
    r.x = c.x - 2.f*b.x + a.x;
    r.y = c.y - 2.f*b.y + a.y;
    r.z = c.z - 2.f*b.z + a.z;
    r.w = c.w - 2.f*b.w + a.w;
    return r;
}

// Persistent kernel: 20 chunks in one dispatch. Halo exchange write-through
// at the IC coherence point. Signaling: publisher increments each neighbor's
// counter (RMW, 8/chunk); waiter load-polls its OWN counter (no RMW polling).
__global__ __launch_bounds__(BLK, 3)
void born_persist(const float* __restrict__ P0, const float* __restrict__ x,
                  float* __restrict__ out,
                  float* __restrict__ f0, float* __restrict__ f1,
                  float* __restrict__ f2p, float* __restrict__ f3p,
                  int* flags, MeasIdx meas)
{
    extern __shared__ float ldsraw[];
    float* lds0 = ldsraw;
    float* lds1 = ldsraw + LDS_FLOATS;
    const int tid = threadIdx.x;
    // XCD-chunk swizzle: all 16 tiles of a plane land on one XCD's L2
    const int sw  = ((blockIdx.x & 7) << 5) | (blockIdx.x >> 3);
    const int pl  = sw >> 4;
    const int t   = sw & 15;
    const int ty  = t >> 2, tx = t & 3;
    const int gy0 = A0 + ty*TILE - HALO;
    const int gx0 = A0 + tx*TILE - HALO;
    const int b   = pl >> 3, rch = pl & 7;
    const size_t pbase = (size_t)pl * PLANE_SZ;

    // neighbor bookkeeping: tid<8 each own one (possibly absent) neighbor;
    // nNb = how many neighbors will increment MY counter per chunk
    const int nNb = ((ty>0)+(ty<3)+1)*((tx>0)+(tx<3)+1) - 1;
    int myNb = -1;
    if (tid < 8){
        int cnt = 0;
        for (int dy=-1; dy<=1; ++dy)
        for (int dx=-1; dx<=1; ++dx){
            if (!dy && !dx) continue;
            int ny = ty+dy, nx = tx+dx;
            if ((unsigned)ny < 4u && (unsigned)nx < 4u){
                if (cnt == tid) myNb = (pl<<4) + (ny<<2) + nx;
                cnt++;
            }
        }
    }

    // ---- per-thread sub-block setup (hoisted across all chunks) ----
    const bool val = (tid < NSB);
    const int gg  = val ? tid : 0;
    const int sby = gg/19, sbx = gg%19;
    const int ly0 = 2*sby, lx0 = 4*sbx;
    const int oC  = ly0*LSTR + lx0;
    int s1 = (ly0-1) >> 1;
    int s2 = (73-ly0) >> 1;
    int s3 = (lx0+1) >> 1;
    int s4 = (73-lx0) >> 1;
    const int sMax = val ? min(min(s1,s2), min(s3,s4)) : -1;
    const int gy = gy0 + ly0, gx = gx0 + lx0;
    const bool win = (gy>=C0 && gy<C0+CW && gx>=C0 && gx<C0+CW);
    const int pofs = win ? (gy*NXg + gx) : 0;

    // rf computed inline (same expression as verified rounds -> bit-identical)
    f4 rfa, rfb2;
    if (win){
        const float* xp = x + (size_t)b*W96SQ + (size_t)(gy-C0)*CW + (gx-C0);
        f4 x0 = *(const f4*)xp;
        f4 x1 = *(const f4*)(xp + CW);
        float tq;
        tq = 1.5f/x0.x; rfa.x  = 1.0f - tq*tq;
        tq = 1.5f/x0.y; rfa.y  = 1.0f - tq*tq;
        tq = 1.5f/x0.z; rfa.z  = 1.0f - tq*tq;
        tq = 1.5f/x0.w; rfa.w  = 1.0f - tq*tq;
        tq = 1.5f/x1.x; rfb2.x = 1.0f - tq*tq;
        tq = 1.5f/x1.y; rfb2.y = 1.0f - tq*tq;
        tq = 1.5f/x1.z; rfb2.z = 1.0f - tq*tq;
        tq = 1.5f/x1.w; rfb2.w = 1.0f - tq*tq;
    } else {
        rfa = make_float4(0.f,0.f,0.f,0.f);
        rfb2 = rfa;
    }
    f4 cfa, cfb;
    {
        float c0v[4], c1v[4];
#pragma unroll
        for (int ii=0; ii<4; ++ii){
            int gxr = gx + ii;
            bool ix = (gxr>=25 && gxr<167);
            float g0 = 0.3f * ((ix && gy  >=25 && gy  <167) ? 1.5f : 1e-6f);
            float g1 = 0.3f * ((ix && gy+1>=25 && gy+1<167) ? 1.5f : 1e-6f);
            c0v[ii] = g0*g0;
            c1v[ii] = g1*g1;
        }
        cfa = make_float4(c0v[0],c0v[1],c0v[2],c0v[3]);
        cfb = make_float4(c1v[0],c1v[1],c1v[2],c1v[3]);
    }

    // receiver ownership (hoisted)
    bool own = false; int loff = 0; size_t obase = 0;
    if (tid < NM){
        int rv = meas.v[tid];
        int ry = rv / NXg, rx = rv % NXg;
        int dy = ry - (A0 + ty*TILE), dx = rx - (A0 + tx*TILE);
        own = ((unsigned)dy < TILE) && ((unsigned)dx < TILE);
        loff = (dy+HALO)*LSTR + (dx+HALO);
        obase = ((size_t)pl*NM + tid)*NT;
    }

    const float* P0r = P0 + (size_t)rch*NT*PLANE_SZ;
    const f4 z4 = make_float4(0.f,0.f,0.f,0.f);

#pragma unroll 1
    for (int ch=0; ch<NCH; ++ch){
        const int J = ch*KSTEP;
        const float* RA = (ch&1) ? f2p : f0;
        const float* RB = (ch&1) ? f3p : f1;
        float*       WA = (ch&1) ? f0  : f2p;
        float*       WB = (ch&1) ? f1  : f3p;

        // ---- P0 chain init loads (independent of neighbors) issued BEFORE
        //      the spin so their latency hides under the wait ----
        f4 Pa0=z4, Pa1=z4, Pb0=z4, Pb1=z4, D0=z4, D1=z4;
        if (win){
            const float* p = P0r + (size_t)J*PLANE_SZ + pofs;
            Pa0 = *(const f4*)p;
            Pa1 = *(const f4*)(p + NXg);
            if (J >= 1){
                Pb0 = *(const f4*)(p - PLANE_SZ);
                Pb1 = *(const f4*)(p - PLANE_SZ + NXg);
            }
            if (J >= 2){
                f4 Pc0 = *(const f4*)(p - 2*PLANE_SZ);
                f4 Pc1 = *(const f4*)(p - 2*PLANE_SZ + NXg);
                D0 = d2c(Pa0, Pb0, Pc0);
                D1 = d2c(Pa1, Pb1, Pc1);
            }
        }

        // ---- wait: my counter reaches nNb*ch (each neighbor +1 per publish).
        //      Plain-load polling; rare RMW refresh as deadlock insurance. ----
        if (ch > 0 && tid == 0){
            const int need = nNb * ch;
            int spins = 0;
            while (ld_flag(&flags[sw]) < need){
                __builtin_amdgcn_s_sleep(2);
                if (++spins >= 16384){
                    spins = 0;
                    if (__hip_atomic_fetch_add(&flags[sw], 0, __ATOMIC_RELAXED,
                                               __HIP_MEMORY_SCOPE_AGENT) >= need) break;
                }
            }
        }
        __syncthreads();

        // ---- refresh LDS ----
        if (ch == 0){
            for (int i = tid; i < 2*LDS_FLOATS; i += BLK) ldsraw[i] = 0.f;
        } else {
            // halo ring only: interior [20,56)^2 of both levels still valid
            for (int i = tid; i < NRING; i += BLK){
                int ly, lx4;
                if (i < 380){ ly = i/19;            lx4 = (i%19)*4; }
                else if (i < 760){ int k=i-380; ly = 56 + k/19; lx4 = (k%19)*4; }
                else { int k=i-760; ly = 20 + k/10; int m=k%10; lx4 = (m<5)? m*4 : 36+m*4; }
                size_t go = pbase + (size_t)(gy0+ly)*NXg + (gx0+lx4);
                float a0=ld_coh(&RA[go  ]), a1=ld_coh(&RA[go+1]);
                float a2=ld_coh(&RA[go+2]), a3=ld_coh(&RA[go+3]);
                float b0=ld_coh(&RB[go  ]), b1=ld_coh(&RB[go+1]);
                float b2=ld_coh(&RB[go+2]), b3=ld_coh(&RB[go+3]);
                int lo = ly*LSTR + lx4;
                *(f4*)&lds0[lo] = make_float4(a0,a1,a2,a3);
                *(f4*)&lds1[lo] = make_float4(b0,b1,b2,b3);
            }
        }

        __syncthreads();

        // center rows of both levels, register-carried
        f4 OA0 = *(const f4*)&lds0[oC];
        f4 OA1 = *(const f4*)&lds0[oC+LSTR];
        f4 OB0 = *(const f4*)&lds1[oC];
        f4 OB1 = *(const f4*)&lds1[oC+LSTR];

#pragma unroll
        for (int s=0; s<KSTEP; ++s){
            float* pa = (s&1) ? lds1 : lds0;
            float* pb = (s&1) ? lds0 : lds1;

            const bool pre = (s+1 < KSTEP) && win && ((s+1) <= sMax);
            f4 Pn0 = z4, Pn1 = z4;
            if (pre){
                const float* p = P0r + (size_t)(J+s+1)*PLANE_SZ + pofs;
                Pn0 = *(const f4*)p;
                Pn1 = *(const f4*)(p + NXg);
            }

            if (s <= sMax){
                f4 C0r = (s&1) ? OA0 : OB0;
                f4 C1r = (s&1) ? OA1 : OB1;
                f4 O0  = (s&1) ? OB0 : OA0;
                f4 O1  = (s&1) ? OB1 : OA1;
                f4 Rm2 = *(const f4*)&pb[oC - 2*LSTR];
                f4 Rm1 = *(const f4*)&pb[oC -   LSTR];
                f4 Rp2 = *(const f4*)&pb[oC + 2*LSTR];
                f4 Rp3 = *(const f4*)&pb[oC + 3*LSTR];
                f2 L0  = *(const f2*)&pb[oC - 2];
                f2 L1  = *(const f2*)&pb[oC + LSTR - 2];
                f2 Q0  = *(const f2*)&pb[oC + 4];
                f2 Q1  = *(const f2*)&pb[oC + LSTR + 4];
                f4 N0 = frow(L0, C0r, Q0, Rm2, Rm1, C1r, Rp2, O0, cfa, rfa,  D0);
                f4 N1 = frow(L1, C1r, Q1, Rm1, C0r, Rp2, Rp3, O1, cfb, rfb2, D1);
                *(f4*)&pa[oC]        = N0;
                *(f4*)&pa[oC + LSTR] = N1;
                if (s&1){ OB0=N0; OB1=N1; } else { OA0=N0; OA1=N1; }
            }

            if (pre){
                if (J+s+1 >= 2){
                    D0 = d2c(Pn0, Pa0, Pb0);
                    D1 = d2c(Pn1, Pa1, Pb1);
                } else { D0 = z4; D1 = z4; }
                Pb0 = Pa0; Pb1 = Pa1;
                Pa0 = Pn0; Pa1 = Pn1;
            }

            __syncthreads();
            if (own) out[obase + (J+s)] = pa[loff];
        }

        // ---- publish interior of the two newest levels (write-through) ----
        if (ch < NCH-1){
            for (int i = tid; i < TILE*(TILE/4); i += BLK){   // 324 groups
                int r = i/9, c4 = (i%9)*4;
                size_t go = pbase + (size_t)(A0 + ty*TILE + r)*NXg + (A0 + tx*TILE + c4);
                int lo = (r+HALO)*LSTR + (c4+HALO);
                f4 vb = *(const f4*)&lds1[lo];   // newest p_{J+9}
                f4 va = *(const f4*)&lds0[lo];   // p_{J+8}
                st_coh(&WB[go  ], vb.x); st_coh(&WB[go+1], vb.y);
                st_coh(&WB[go+2], vb.z); st_coh(&WB[go+3], vb.w);
                st_coh(&WA[go  ], va.x); st_coh(&WA[go+1], va.y);
                st_coh(&WA[go+2], va.z); st_coh(&WA[go+3], va.w);
            }
            // drain own stores to the coherence point; block-wide complete;
            // then signal: +1 into EACH neighbor's counter
            asm volatile("s_waitcnt vmcnt(0)" ::: "memory");
            __syncthreads();
            if (tid < 8 && myNb >= 0)
                __hip_atomic_fetch_add(&flags[myNb], 1, __ATOMIC_RELAXED,
                                       __HIP_MEMORY_SCOPE_AGENT);
        }
    }
}

extern "C" void kernel_launch(void* const* d_in, const int* in_sizes, int n_in,
                              void* d_out, int out_size, void* d_ws, size_t ws_size,
                              hipStream_t stream)
{
    const float* x  = (const float*)d_in[0];   // (2,1,96,96) f32
    const float* P0 = (const float*)d_in[1];   // (1,8,200,192,192) f32
    float* out = (float*)d_out;                // (2,8,32,200) f32

    float* F   = (float*)d_ws;
    float* f0  = F;
    float* f1  = F + (size_t)TOTAL;
    float* f2p = F + 2*(size_t)TOTAL;
    float* f3p = F + 3*(size_t)TOTAL;
    int*  flags = (int*)(F + 4*(size_t)TOTAL);

    // zero field buffers (exterior cells must stay 0) + flags (must start 0)
    size_t zbytes = (size_t)4*TOTAL*sizeof(float) + 256*sizeof(int);
    hipMemsetAsync(d_ws, 0, zbytes, stream);

    MeasIdx meas;
    for (int k=0;k<NM;++k){
        double th = 2.0*M_PI*(double)k/(double)NM;
        int mx = (int)(96.0 + 70.0*cos(th));
        int my = (int)(96.0 + 70.0*sin(th));
        meas.v[k] = mx*NXg + my;
    }

    born_persist<<<256, BLK, LDS_FORCE, stream>>>(P0, x, out,
                                                  f0, f1, f2p, f3p, flags, meas);
}

// Round 10
// 232.923 us; speedup vs baseline: 1.3866x; 1.3866x over previous
//
#include <hip/hip_runtime.h>
#include <math.h>

// ---------------- geometry constants ----------------
#define NXg      192
#define PLANE_SZ (NXg*NXg)            // 36864
#define PLANES   16                   // B(2) * NR(8)
#define TOTAL    (PLANES*PLANE_SZ)
#define NT       200
#define NM       32
#define CW       96                   // central window width
#define C0       48                   // central window origin
#define W96SQ    (CW*CW)
#define A0       24                   // active domain [24,168)^2 ; outside ~0 (coef 9e-14)
#define TILE     36                   // interior tile, 16 tiles/plane -> 256 blocks
#define HALO     20                   // 2 cells/step * 10 steps
#define EXPW     76                   // TILE + 2*HALO
#define LSTR     84                   // LDS row stride
#define KSTEP    10
#define NLAUNCH  20
#define NSB      (38*19)              // 722 sub-blocks (2 rows x 4 cols)
#define BLK      768                  // 12 waves/CU

struct MeasIdx { int v[NM]; };
typedef float4 f4;
typedef float2 f2;

// Reassociated stencil: 16*(xm1+xp1+ym1+yp1) - (xm2+xp2+ym2+yp2) - 60*c,
// with coef/12 pre-folded into CFs. 11 VALU ops/point vs ~21 for the
// factored form. NOT bit-identical to rounds 1-9 (reassociation); threshold
// headroom is 9x (absmax 3.05e-5 vs 2.7e-4).
__device__ __forceinline__ f4 frow2(f2 L, f4 C, f2 Q,
                                    f4 m2, f4 m1, f4 p1, f4 p2,
                                    f4 O, f4 CFs, f4 RF, f4 D2)
{
    f4 r;
    // col 0: xm2=L.x xm1=L.y xp1=C.y xp2=C.z
    {
        float s16 = (L.y + C.y) + (m1.x + p1.x);
        float s1  = (L.x + C.z) + (m2.x + p2.x);
        float st  = fmaf(16.f, s16, -s1);
        st = fmaf(-60.f, C.x, st);
        float p = fmaf(2.f, C.x, -O.x);
        p = fmaf(CFs.x, st, p);
        r.x = fmaf(RF.x, D2.x, p);
    }
    // col 1: xm2=L.y xm1=C.x xp1=C.z xp2=C.w
    {
        float s16 = (C.x + C.z) + (m1.y + p1.y);
        float s1  = (L.y + C.w) + (m2.y + p2.y);
        float st  = fmaf(16.f, s16, -s1);
        st = fmaf(-60.f, C.y, st);
        float p = fmaf(2.f, C.y, -O.y);
        p = fmaf(CFs.y, st, p);
        r.y = fmaf(RF.y, D2.y, p);
    }
    // col 2: xm2=C.x xm1=C.y xp1=C.w xp2=Q.x
    {
        float s16 = (C.y + C.w) + (m1.z + p1.z);
        float s1  = (C.x + Q.x) + (m2.z + p2.z);
        float st  = fmaf(16.f, s16, -s1);
        st = fmaf(-60.f, C.z, st);
        float p = fmaf(2.f, C.z, -O.z);
        p = fmaf(CFs.z, st, p);
        r.z = fmaf(RF.z, D2.z, p);
    }
    // col 3: xm2=C.y xm1=C.z xp1=Q.x xp2=Q.y
    {
        float s16 = (C.z + Q.x) + (m1.w + p1.w);
        float s1  = (C.y + Q.y) + (m2.w + p2.w);
        float st  = fmaf(16.f, s16, -s1);
        st = fmaf(-60.f, C.w, st);
        float p = fmaf(2.f, C.w, -O.w);
        p = fmaf(CFs.w, st, p);
        r.w = fmaf(RF.w, D2.w, p);
    }
    return r;
}

__device__ __forceinline__ f4 d2c(f4 c, f4 b, f4 a){
    f4 r;
    r.x = c.x - 2.f*b.x + a.x;
    r.y = c.y - 2.f*b.y + a.y;
    r.z = c.z - 2.f*b.z + a.z;
    r.w = c.w - 2.f*b.w + a.w;
    return r;
}

// Advance KSTEP=10 steps of a 36x36 interior tile of one plane, in LDS.
// J==0 zero-fills LDS (no memset kernel); halo loads predicated to zero
// outside the active domain; rf computed inline (no rf kernel).
__global__ __launch_bounds__(BLK, 3)
void step_fused(const float* __restrict__ RA, const float* __restrict__ RB,
                float* __restrict__ WA, float* __restrict__ WB,
                const float* __restrict__ P0, const float* __restrict__ x,
                float* __restrict__ out, int J, MeasIdx meas)
{
    __shared__ float lds0[EXPW*LSTR];
    __shared__ float lds1[EXPW*LSTR];
    const int tid = threadIdx.x;
    // XCD-chunk swizzle: all 16 tiles of a plane land on one XCD's L2
    const int sw  = ((blockIdx.x & 7) << 5) | (blockIdx.x >> 3);
    const int pl  = sw >> 4;
    const int t   = sw & 15;
    const int ty  = t >> 2, tx = t & 3;
    const int gy0 = A0 + ty*TILE - HALO;
    const int gx0 = A0 + tx*TILE - HALO;
    const int b   = pl >> 3, rch = pl & 7;
    const size_t pbase = (size_t)pl * PLANE_SZ;
    const f4 z4 = make_float4(0.f,0.f,0.f,0.f);

    // ---- load EXPW x EXPW tiles of both levels; zero outside active domain
    //      or on the first launch (initial state is zero) ----
    {
        const bool zf = (J == 0);
        for (int i = tid; i < EXPW*19; i += BLK){  // 76*19 = 1444 f4 groups
            int ly = i/19, lx4 = (i%19)*4;
            int gyr = gy0 + ly, gxg = gx0 + lx4;   // group never straddles the boundary
            bool ok = !zf && ((unsigned)(gyr - A0) < 144u)
                          && ((unsigned)(gxg - A0) < 144u);
            f4 va = z4, vb = z4;
            if (ok){
                size_t go = pbase + (size_t)gyr*NXg + gxg;
                va = *(const f4*)&RA[go];
                vb = *(const f4*)&RB[go];
            }
            int lo = ly*LSTR + lx4;
            *(f4*)&lds0[lo] = va;
            *(f4*)&lds1[lo] = vb;
        }
    }

    // ---- per-thread sub-block setup ----
    const bool val = (tid < NSB);
    const int gg  = val ? tid : 0;
    const int sby = gg/19, sbx = gg%19;
    const int ly0 = 2*sby, lx0 = 4*sbx;
    const int oC  = ly0*LSTR + lx0;
    int s1 = (ly0-1) >> 1;
    int s2 = (73-ly0) >> 1;
    int s3 = (lx0+1) >> 1;
    int s4 = (73-lx0) >> 1;
    const int sMax = val ? min(min(s1,s2), min(s3,s4)) : -1;
    const int gy = gy0 + ly0, gx = gx0 + lx0;
    const bool win = (gy>=C0 && gy<C0+CW && gx>=C0 && gx<C0+CW);
    const int pofs = win ? (gy*NXg + gx) : 0;

    // rf inline: same "t=1.5f/x; 1-t*t" expression as verified rounds
    f4 rfa, rfb2;
    if (win){
        const float* xp = x + (size_t)b*W96SQ + (size_t)(gy-C0)*CW + (gx-C0);
        f4 x0 = *(const f4*)xp;
        f4 x1 = *(const f4*)(xp + CW);
        float tq;
        tq = 1.5f/x0.x; rfa.x  = 1.0f - tq*tq;
        tq = 1.5f/x0.y; rfa.y  = 1.0f - tq*tq;
        tq = 1.5f/x0.z; rfa.z  = 1.0f - tq*tq;
        tq = 1.5f/x0.w; rfa.w  = 1.0f - tq*tq;
        tq = 1.5f/x1.x; rfb2.x = 1.0f - tq*tq;
        tq = 1.5f/x1.y; rfb2.y = 1.0f - tq*tq;
        tq = 1.5f/x1.z; rfb2.z = 1.0f - tq*tq;
        tq = 1.5f/x1.w; rfb2.w = 1.0f - tq*tq;
    } else {
        rfa = z4; rfb2 = z4;
    }
    // CFs = coef/12, pre-folded for the reassociated stencil
    f4 cfa, cfb;
    {
        float c0v[4], c1v[4];
#pragma unroll
        for (int ii=0; ii<4; ++ii){
            int gxr = gx + ii;
            bool ix = (gxr>=25 && gxr<167);
            float g0 = 0.3f * ((ix && gy  >=25 && gy  <167) ? 1.5f : 1e-6f);
            float g1 = 0.3f * ((ix && gy+1>=25 && gy+1<167) ? 1.5f : 1e-6f);
            c0v[ii] = (g0*g0)*(1.0f/12.0f);
            c1v[ii] = (g1*g1)*(1.0f/12.0f);
        }
        cfa = make_float4(c0v[0],c0v[1],c0v[2],c0v[3]);
        cfb = make_float4(c1v[0],c1v[1],c1v[2],c1v[3]);
    }

    // receiver ownership (hoisted)
    bool own = false; int loff = 0; size_t obase = 0;
    if (tid < NM){
        int rv = meas.v[tid];
        int ry = rv / NXg, rx = rv % NXg;
        int dy = ry - (A0 + ty*TILE), dx = rx - (A0 + tx*TILE);
        own = ((unsigned)dy < TILE) && ((unsigned)dx < TILE);
        loff = (dy+HALO)*LSTR + (dx+HALO);
        obase = ((size_t)pl*NM + tid)*NT;
    }

    // ---- P0 register chain: Pa=P0[J], Pb=P0[J-1]; D = d2 for step 0 ----
    const float* P0r = P0 + (size_t)rch*NT*PLANE_SZ;
    f4 Pa0=z4, Pa1=z4, Pb0=z4, Pb1=z4, D0=z4, D1=z4;
    if (win){
        const float* p = P0r + (size_t)J*PLANE_SZ + pofs;
        Pa0 = *(const f4*)p;
        Pa1 = *(const f4*)(p + NXg);
        if (J >= 1){
            Pb0 = *(const f4*)(p - PLANE_SZ);
            Pb1 = *(const f4*)(p - PLANE_SZ + NXg);
        }
        if (J >= 2){
            f4 Pc0 = *(const f4*)(p - 2*PLANE_SZ);
            f4 Pc1 = *(const f4*)(p - 2*PLANE_SZ + NXg);
            D0 = d2c(Pa0, Pb0, Pc0);
            D1 = d2c(Pa1, Pb1, Pc1);
        }
    }

    __syncthreads();

    // center rows of both levels, register-carried
    f4 OA0 = *(const f4*)&lds0[oC];
    f4 OA1 = *(const f4*)&lds0[oC+LSTR];
    f4 OB0 = *(const f4*)&lds1[oC];
    f4 OB1 = *(const f4*)&lds1[oC+LSTR];

#pragma unroll
    for (int s=0; s<KSTEP; ++s){
        float* pa = (s&1) ? lds1 : lds0;      // level overwritten with p_{J+s}
        float* pb = (s&1) ? lds0 : lds1;      // stencil source p_{J+s-1}

        const bool pre = (s+1 < KSTEP) && win && ((s+1) <= sMax);
        f4 Pn0 = z4, Pn1 = z4;
        if (pre){
            const float* p = P0r + (size_t)(J+s+1)*PLANE_SZ + pofs;
            Pn0 = *(const f4*)p;
            Pn1 = *(const f4*)(p + NXg);
        }

        if (s <= sMax){
            f4 C0r = (s&1) ? OA0 : OB0;       // pb center rows (own)
            f4 C1r = (s&1) ? OA1 : OB1;
            f4 O0  = (s&1) ? OB0 : OA0;       // pa center rows (p_{s-2})
            f4 O1  = (s&1) ? OB1 : OA1;
            f4 Rm2 = *(const f4*)&pb[oC - 2*LSTR];
            f4 Rm1 = *(const f4*)&pb[oC -   LSTR];
            f4 Rp2 = *(const f4*)&pb[oC + 2*LSTR];
            f4 Rp3 = *(const f4*)&pb[oC + 3*LSTR];
            f2 L0  = *(const f2*)&pb[oC - 2];
            f2 L1  = *(const f2*)&pb[oC + LSTR - 2];
            f2 Q0  = *(const f2*)&pb[oC + 4];
            f2 Q1  = *(const f2*)&pb[oC + LSTR + 4];
            f4 N0 = frow2(L0, C0r, Q0, Rm2, Rm1, C1r, Rp2, O0, cfa, rfa,  D0);
            f4 N1 = frow2(L1, C1r, Q1, Rm1, C0r, Rp2, Rp3, O1, cfb, rfb2, D1);
            *(f4*)&pa[oC]        = N0;
            *(f4*)&pa[oC + LSTR] = N1;
            if (s&1){ OB0=N0; OB1=N1; } else { OA0=N0; OA1=N1; }
        }

        if (pre){
            if (J+s+1 >= 2){
                D0 = d2c(Pn0, Pa0, Pb0);
                D1 = d2c(Pn1, Pa1, Pb1);
            } else { D0 = z4; D1 = z4; }
            Pb0 = Pa0; Pb1 = Pa1;
            Pa0 = Pn0; Pa1 = Pn1;
        }

        __syncthreads();
        if (own) out[obase + (J+s)] = pa[loff];
    }

    // ---- write back interior of the last two levels ----
    // KSTEP=10: s=9 (odd) wrote lds1 -> lds1 = newest p_{J+9}, lds0 = p_{J+8}
    for (int i = tid; i < TILE*(TILE/4); i += BLK){   // 36*9 = 324 groups
        int r = i/9, c4 = (i%9)*4;
        size_t go = pbase + (size_t)(A0 + ty*TILE + r)*NXg + (A0 + tx*TILE + c4);
        int lo = (r+HALO)*LSTR + (c4+HALO);
        *(f4*)&WB[go] = *(const f4*)&lds1[lo];
        *(f4*)&WA[go] = *(const f4*)&lds0[lo];
    }
}

extern "C" void kernel_launch(void* const* d_in, const int* in_sizes, int n_in,
                              void* d_out, int out_size, void* d_ws, size_t ws_size,
                              hipStream_t stream)
{
    const float* x  = (const float*)d_in[0];   // (2,1,96,96) f32
    const float* P0 = (const float*)d_in[1];   // (1,8,200,192,192) f32
    float* out = (float*)d_out;                // (2,8,32,200) f32

    float* F   = (float*)d_ws;
    float* f0  = F;
    float* f1  = F + (size_t)TOTAL;
    float* f2p = F + 2*(size_t)TOTAL;
    float* f3p = F + 3*(size_t)TOTAL;

    // No memset: first launch (J==0) zero-fills LDS; later launches read only
    // interior cells written by the previous launch, or predicated zeros.

    MeasIdx meas;
    for (int k=0;k<NM;++k){
        double th = 2.0*M_PI*(double)k/(double)NM;
        int mx = (int)(96.0 + 70.0*cos(th));
        int my = (int)(96.0 + 70.0*sin(th));
        meas.v[k] = mx*NXg + my;
    }

    float *RA=f0, *RB=f1, *WA=f2p, *WB=f3p;
    for (int L=0; L<NLAUNCH; ++L){
        step_fused<<<256, BLK, 0, stream>>>(RA,RB,WA,WB,P0,x,out,L*KSTEP,meas);
        float* tsw;
        tsw=RA; RA=WA; WA=tsw;
        tsw=RB; RB=WB; WB=tsw;
    }
}

// Round 11
// 223.920 us; speedup vs baseline: 1.4423x; 1.0402x over previous
//
#include <hip/hip_runtime.h>
#include <math.h>

// ---------------- geometry constants ----------------
#define NXg      192
#define PLANE_SZ (NXg*NXg)            // 36864
#define PLANES   16                   // B(2) * NR(8)
#define TOTAL    (PLANES*PLANE_SZ)
#define NT       200
#define NM       32
#define CW       96                   // central window width
#define C0       48                   // central window origin
#define W96SQ    (CW*CW)
#define A0       24                   // active domain [24,168)^2 ; outside ~0 (coef 9e-14)
#define TILE     36                   // interior tile, 16 tiles/plane -> 256 blocks
#define HALO     20                   // 2 cells/step * 10 steps
#define EXPW     76                   // TILE + 2*HALO
#define LSTR     84                   // LDS row stride
#define KSTEP    10
#define NLAUNCH  20
#define NSB      (38*19)              // 722 sub-blocks (2 rows x 4 cols)
#define BLK      768                  // 12 waves/CU

struct MeasIdx { int v[NM]; };
typedef float4 f4;
typedef float2 f2;

// LDS-only barrier: skips the vmcnt(0) drain __syncthreads would emit, so
// in-flight global (P0) prefetch loads can span the barrier. All cross-thread
// data in this kernel moves through LDS (ds ops retire under lgkmcnt);
// global loads are consumed by the issuing thread via register scoreboard.
__device__ __forceinline__ void barrier_lds(){
    asm volatile("s_waitcnt lgkmcnt(0)\n\ts_barrier" ::: "memory");
}

// Reassociated stencil (verified R10): 16*(xm1+xp1+ym1+yp1) - (xm2+xp2+ym2+yp2)
// - 60*c, coef/12 pre-folded into CFs. 11 VALU ops/point.
__device__ __forceinline__ f4 frow2(f2 L, f4 C, f2 Q,
                                    f4 m2, f4 m1, f4 p1, f4 p2,
                                    f4 O, f4 CFs, f4 RF, f4 D2)
{
    f4 r;
    {
        float s16 = (L.y + C.y) + (m1.x + p1.x);
        float s1  = (L.x + C.z) + (m2.x + p2.x);
        float st  = fmaf(16.f, s16, -s1);
        st = fmaf(-60.f, C.x, st);
        float p = fmaf(2.f, C.x, -O.x);
        p = fmaf(CFs.x, st, p);
        r.x = fmaf(RF.x, D2.x, p);
    }
    {
        float s16 = (C.x + C.z) + (m1.y + p1.y);
        float s1  = (L.y + C.w) + (m2.y + p2.y);
        float st  = fmaf(16.f, s16, -s1);
        st = fmaf(-60.f, C.y, st);
        float p = fmaf(2.f, C.y, -O.y);
        p = fmaf(CFs.y, st, p);
        r.y = fmaf(RF.y, D2.y, p);
    }
    {
        float s16 = (C.y + C.w) + (m1.z + p1.z);
        float s1  = (C.x + Q.x) + (m2.z + p2.z);
        float st  = fmaf(16.f, s16, -s1);
        st = fmaf(-60.f, C.z, st);
        float p = fmaf(2.f, C.z, -O.z);
        p = fmaf(CFs.z, st, p);
        r.z = fmaf(RF.z, D2.z, p);
    }
    {
        float s16 = (C.z + Q.x) + (m1.w + p1.w);
        float s1  = (C.y + Q.y) + (m2.w + p2.w);
        float st  = fmaf(16.f, s16, -s1);
        st = fmaf(-60.f, C.w, st);
        float p = fmaf(2.f, C.w, -O.w);
        p = fmaf(CFs.w, st, p);
        r.w = fmaf(RF.w, D2.w, p);
    }
    return r;
}

__device__ __forceinline__ f4 d2c(f4 c, f4 b, f4 a){
    f4 r;
    r.x = c.x - 2.f*b.x + a.x;
    r.y = c.y - 2.f*b.y + a.y;
    r.z = c.z - 2.f*b.z + a.z;
    r.w = c.w - 2.f*b.w + a.w;
    return r;
}

// Advance KSTEP=10 steps of a 36x36 interior tile of one plane, in LDS.
// P0 prefetch spans the (lgkmcnt-only) barrier; chain roll happens after it.
__global__ __launch_bounds__(BLK, 3)
void step_fused(const float* __restrict__ RA, const float* __restrict__ RB,
                float* __restrict__ WA, float* __restrict__ WB,
                const float* __restrict__ P0, const float* __restrict__ x,
                float* __restrict__ out, int J, MeasIdx meas)
{
    __shared__ float lds0[EXPW*LSTR];
    __shared__ float lds1[EXPW*LSTR];
    const int tid = threadIdx.x;
    // XCD-chunk swizzle: all 16 tiles of a plane land on one XCD's L2
    const int sw  = ((blockIdx.x & 7) << 5) | (blockIdx.x >> 3);
    const int pl  = sw >> 4;
    const int t   = sw & 15;
    const int ty  = t >> 2, tx = t & 3;
    const int gy0 = A0 + ty*TILE - HALO;
    const int gx0 = A0 + tx*TILE - HALO;
    const int b   = pl >> 3, rch = pl & 7;
    const size_t pbase = (size_t)pl * PLANE_SZ;
    const f4 z4 = make_float4(0.f,0.f,0.f,0.f);

    // ---- load EXPW x EXPW tiles of both levels; zero outside active domain
    //      or on the first launch (initial state is zero) ----
    {
        const bool zf = (J == 0);
        for (int i = tid; i < EXPW*19; i += BLK){  // 76*19 = 1444 f4 groups
            int ly = i/19, lx4 = (i%19)*4;
            int gyr = gy0 + ly, gxg = gx0 + lx4;
            bool ok = !zf && ((unsigned)(gyr - A0) < 144u)
                          && ((unsigned)(gxg - A0) < 144u);
            f4 va = z4, vb = z4;
            if (ok){
                size_t go = pbase + (size_t)gyr*NXg + gxg;
                va = *(const f4*)&RA[go];
                vb = *(const f4*)&RB[go];
            }
            int lo = ly*LSTR + lx4;
            *(f4*)&lds0[lo] = va;
            *(f4*)&lds1[lo] = vb;
        }
    }

    // ---- per-thread sub-block setup ----
    const bool val = (tid < NSB);
    const int gg  = val ? tid : 0;
    const int sby = gg/19, sbx = gg%19;
    const int ly0 = 2*sby, lx0 = 4*sbx;
    const int oC  = ly0*LSTR + lx0;
    int s1 = (ly0-1) >> 1;
    int s2 = (73-ly0) >> 1;
    int s3 = (lx0+1) >> 1;
    int s4 = (73-lx0) >> 1;
    const int sMax = val ? min(min(s1,s2), min(s3,s4)) : -1;
    const int gy = gy0 + ly0, gx = gx0 + lx0;
    const bool win = (gy>=C0 && gy<C0+CW && gx>=C0 && gx<C0+CW);
    const int pofs = win ? (gy*NXg + gx) : 0;

    // rf inline (verified R8-R10)
    f4 rfa, rfb2;
    if (win){
        const float* xp = x + (size_t)b*W96SQ + (size_t)(gy-C0)*CW + (gx-C0);
        f4 x0 = *(const f4*)xp;
        f4 x1 = *(const f4*)(xp + CW);
        float tq;
        tq = 1.5f/x0.x; rfa.x  = 1.0f - tq*tq;
        tq = 1.5f/x0.y; rfa.y  = 1.0f - tq*tq;
        tq = 1.5f/x0.z; rfa.z  = 1.0f - tq*tq;
        tq = 1.5f/x0.w; rfa.w  = 1.0f - tq*tq;
        tq = 1.5f/x1.x; rfb2.x = 1.0f - tq*tq;
        tq = 1.5f/x1.y; rfb2.y = 1.0f - tq*tq;
        tq = 1.5f/x1.z; rfb2.z = 1.0f - tq*tq;
        tq = 1.5f/x1.w; rfb2.w = 1.0f - tq*tq;
    } else {
        rfa = z4; rfb2 = z4;
    }
    // CFs = coef/12, pre-folded for the reassociated stencil
    f4 cfa, cfb;
    {
        float c0v[4], c1v[4];
#pragma unroll
        for (int ii=0; ii<4; ++ii){
            int gxr = gx + ii;
            bool ix = (gxr>=25 && gxr<167);
            float g0 = 0.3f * ((ix && gy  >=25 && gy  <167) ? 1.5f : 1e-6f);
            float g1 = 0.3f * ((ix && gy+1>=25 && gy+1<167) ? 1.5f : 1e-6f);
            c0v[ii] = (g0*g0)*(1.0f/12.0f);
            c1v[ii] = (g1*g1)*(1.0f/12.0f);
        }
        cfa = make_float4(c0v[0],c0v[1],c0v[2],c0v[3]);
        cfb = make_float4(c1v[0],c1v[1],c1v[2],c1v[3]);
    }

    // receiver ownership (hoisted)
    bool own = false; int loff = 0; size_t obase = 0;
    if (tid < NM){
        int rv = meas.v[tid];
        int ry = rv / NXg, rx = rv % NXg;
        int dy = ry - (A0 + ty*TILE), dx = rx - (A0 + tx*TILE);
        own = ((unsigned)dy < TILE) && ((unsigned)dx < TILE);
        loff = (dy+HALO)*LSTR + (dx+HALO);
        obase = ((size_t)pl*NM + tid)*NT;
    }

    // ---- P0 register chain: Pa=P0[J], Pb=P0[J-1]; D = d2 for step 0 ----
    const float* P0r = P0 + (size_t)rch*NT*PLANE_SZ;
    f4 Pa0=z4, Pa1=z4, Pb0=z4, Pb1=z4, D0=z4, D1=z4;
    if (win){
        const float* p = P0r + (size_t)J*PLANE_SZ + pofs;
        Pa0 = *(const f4*)p;
        Pa1 = *(const f4*)(p + NXg);
        if (J >= 1){
            Pb0 = *(const f4*)(p - PLANE_SZ);
            Pb1 = *(const f4*)(p - PLANE_SZ + NXg);
        }
        if (J >= 2){
            f4 Pc0 = *(const f4*)(p - 2*PLANE_SZ);
            f4 Pc1 = *(const f4*)(p - 2*PLANE_SZ + NXg);
            D0 = d2c(Pa0, Pb0, Pc0);
            D1 = d2c(Pa1, Pb1, Pc1);
        }
    }

    barrier_lds();

    // center rows of both levels, register-carried
    f4 OA0 = *(const f4*)&lds0[oC];
    f4 OA1 = *(const f4*)&lds0[oC+LSTR];
    f4 OB0 = *(const f4*)&lds1[oC];
    f4 OB1 = *(const f4*)&lds1[oC+LSTR];

#pragma unroll
    for (int s=0; s<KSTEP; ++s){
        float* pa = (s&1) ? lds1 : lds0;      // level overwritten with p_{J+s}
        float* pb = (s&1) ? lds0 : lds1;      // stencil source p_{J+s-1}

        // issue next-step P0 loads; they stay in flight across the barrier
        const bool pre = (s+1 < KSTEP) && win && ((s+1) <= sMax);
        f4 Pn0 = z4, Pn1 = z4;
        if (pre){
            const float* p = P0r + (size_t)(J+s+1)*PLANE_SZ + pofs;
            Pn0 = *(const f4*)p;
            Pn1 = *(const f4*)(p + NXg);
        }

        if (s <= sMax){
            f4 C0r = (s&1) ? OA0 : OB0;       // pb center rows (own)
            f4 C1r = (s&1) ? OA1 : OB1;
            f4 O0  = (s&1) ? OB0 : OA0;       // pa center rows (p_{s-2})
            f4 O1  = (s&1) ? OB1 : OA1;
            f4 Rm2 = *(const f4*)&pb[oC - 2*LSTR];
            f4 Rm1 = *(const f4*)&pb[oC -   LSTR];
            f4 Rp2 = *(const f4*)&pb[oC + 2*LSTR];
            f4 Rp3 = *(const f4*)&pb[oC + 3*LSTR];
            f2 L0  = *(const f2*)&pb[oC - 2];
            f2 L1  = *(const f2*)&pb[oC + LSTR - 2];
            f2 Q0  = *(const f2*)&pb[oC + 4];
            f2 Q1  = *(const f2*)&pb[oC + LSTR + 4];
            f4 N0 = frow2(L0, C0r, Q0, Rm2, Rm1, C1r, Rp2, O0, cfa, rfa,  D0);
            f4 N1 = frow2(L1, C1r, Q1, Rm1, C0r, Rp2, Rp3, O1, cfb, rfb2, D1);
            *(f4*)&pa[oC]        = N0;
            *(f4*)&pa[oC + LSTR] = N1;
            if (s&1){ OB0=N0; OB1=N1; } else { OA0=N0; OA1=N1; }
        }

        barrier_lds();

        // roll the d2 chain AFTER the barrier: the Pn loads had the whole
        // compute phase + barrier to land (pure register math, value-identical)
        if (pre){
            if (J+s+1 >= 2){
                D0 = d2c(Pn0, Pa0, Pb0);
                D1 = d2c(Pn1, Pa1, Pb1);
            } else { D0 = z4; D1 = z4; }
            Pb0 = Pa0; Pb1 = Pa1;
            Pa0 = Pn0; Pa1 = Pn1;
        }

        if (own) out[obase + (J+s)] = pa[loff];
    }

    // ---- write back interior of the last two levels ----
    // KSTEP=10: s=9 (odd) wrote lds1 -> lds1 = newest p_{J+9}, lds0 = p_{J+8}
    for (int i = tid; i < TILE*(TILE/4); i += BLK){   // 36*9 = 324 groups
        int r = i/9, c4 = (i%9)*4;
        size_t go = pbase + (size_t)(A0 + ty*TILE + r)*NXg + (A0 + tx*TILE + c4);
        int lo = (r+HALO)*LSTR + (c4+HALO);
        *(f4*)&WB[go] = *(const f4*)&lds1[lo];
        *(f4*)&WA[go] = *(const f4*)&lds0[lo];
    }
}

extern "C" void kernel_launch(void* const* d_in, const int* in_sizes, int n_in,
                              void* d_out, int out_size, void* d_ws, size_t ws_size,
                              hipStream_t stream)
{
    const float* x  = (const float*)d_in[0];   // (2,1,96,96) f32
    const float* P0 = (const float*)d_in[1];   // (1,8,200,192,192) f32
    float* out = (float*)d_out;                // (2,8,32,200) f32

    float* F   = (float*)d_ws;
    float* f0  = F;
    float* f1  = F + (size_t)TOTAL;
    float* f2p = F + 2*(size_t)TOTAL;
    float* f3p = F + 3*(size_t)TOTAL;

    MeasIdx meas;
    for (int k=0;k<NM;++k){
        double th = 2.0*M_PI*(double)k/(double)NM;
        int mx = (int)(96.0 + 70.0*cos(th));
        int my = (int)(96.0 + 70.0*sin(th));
        meas.v[k] = mx*NXg + my;
    }

    float *RA=f0, *RB=f1, *WA=f2p, *WB=f3p;
    for (int L=0; L<NLAUNCH; ++L){
        step_fused<<<256, BLK, 0, stream>>>(RA,RB,WA,WB,P0,x,out,L*KSTEP,meas);
        float* tsw;
        tsw=RA; RA=WA; WA=tsw;
        tsw=RB; RB=WB; WB=tsw;
    }
}